// Round 10
// baseline (555.535 us; speedup 1.0000x reference)
//
#include <hip/hip_runtime.h>
#include <math.h>

#define D 128
#define H 128
#define BQ 1024
#define M 512
#define NNODES 500000
#define K_MAX 8
#define SHORT 16
#define NSCORE (BQ * 2)            // score units: (row b, m-half), 4 tiles each
#define NCOPY 2048                 // copy units
#define COPY_N4 ((long)NNODES * D / 4)

typedef __attribute__((ext_vector_type(8))) short bf16x8;
typedef __attribute__((ext_vector_type(4))) float f32x4;
typedef __attribute__((ext_vector_type(4))) unsigned u32x4;

// RNE fp32->bf16, packed pair
static __device__ __forceinline__ unsigned pack2bf(float a, float b) {
    unsigned ua = __float_as_uint(a);
    unsigned ub = __float_as_uint(b);
    ua = ua + 0x7fffu + ((ua >> 16) & 1u);
    ub = ub + 0x7fffu + ((ub >> 16) & 1u);
    return (ua >> 16) | (ub & 0xffff0000u);
}

// ---------------------------------------------------------------------------
// Phase 0: W1 bottom half -> bf16, LINEAR [h][k] image (read direct from
// L1/L2 by score lanes; no LDS staging anymore).
// ---------------------------------------------------------------------------
__global__ void wconv_kernel(const float* __restrict__ W1,
                             unsigned short* __restrict__ wT) {
    const int idx = blockIdx.x * 256 + threadIdx.x;  // 0..16383
    const int h = idx >> 7;
    const int k = idx & 127;
    const float v = W1[(long)(D + k) * H + h];
    wT[idx] = (unsigned short)pack2bf(v, 0.f);
}

// ---------------------------------------------------------------------------
// Phase 1: qh[b][h] = b1[h] + embed[query[b]] . W1top   (fp32)
// ---------------------------------------------------------------------------
__global__ void qproj_kernel(const float* __restrict__ embed,
                             const float* __restrict__ W1,
                             const float* __restrict__ b1,
                             const int* __restrict__ query_idx,
                             float* __restrict__ qh) {
    __shared__ float qrow[D];
    const int b = blockIdx.x;
    const int t = threadIdx.x;
    const long qi = query_idx[b];
    qrow[t] = embed[qi * D + t];
    __syncthreads();
    float acc = b1[t];
#pragma unroll 8
    for (int d = 0; d < D; ++d)
        acc = fmaf(qrow[d], W1[d * H + t], acc);
    qh[b * H + t] = acc;
}

// ---------------------------------------------------------------------------
// Phase 2 (FUSED, ZERO LDS): score + copy heterogeneous launch.
//   bid odd  -> score unit (2048): (b, m-half), 4 m-tiles; A gathered direct
//               to registers; B fragments read direct from global wT
//               (32 KB, L1/L2-hot). No LDS, no barriers at all.
//   bid even -> copy unit (2048): nontemporal f32x4 stream.
// LDS=0 + VGPR<=64 (launch_bounds 8 blocks/CU) -> 32 waves/CU residency,
// so the copy tail runs at standalone streaming speed (~6.5 TB/s).
// ---------------------------------------------------------------------------
__global__ __launch_bounds__(256, 8)
void fused_kernel(const float* __restrict__ embed,
                  const unsigned short* __restrict__ wT,
                  const float* __restrict__ W2,
                  const float* __restrict__ b2,
                  const int* __restrict__ cand_idx,
                  const float* __restrict__ qh,
                  float* __restrict__ scores,
                  const f32x4* __restrict__ nf_src,
                  f32x4* __restrict__ nf_dst) {
    const int bid = blockIdx.x;
    const int t   = threadIdx.x;

    if ((bid & 1) == 0) {
        // ---------------- copy unit: nontemporal streaming -----------------
        const int cid = bid >> 1;                     // 0..NCOPY-1
        long i = (long)cid * 256 + t;
        const long stride = (long)NCOPY * 256;
        for (; i < COPY_N4; i += stride) {
            const f32x4 v = __builtin_nontemporal_load(&nf_src[i]);
            __builtin_nontemporal_store(v, &nf_dst[i]);
        }
        return;
    }

    // ------------------- score unit: (b, half), 4 m-tiles ------------------
    const int sid  = bid >> 1;           // 0..NSCORE-1
    const int b    = sid >> 1;           // 0..BQ-1
    const int half = sid & 1;            // m-offset half*256

    const int lane = t & 63;
    const int w    = t >> 6;       // wave id = edge band within tile
    const int g    = lane >> 4;    // k-group
    const int c    = lane & 15;    // row (edge) / col (h) within band

    // hoist per-row operands: qh and W2 at h = cb*16+c
    float qv[8], w2[8];
#pragma unroll
    for (int cb = 0; cb < 8; ++cb) {
        qv[cb] = qh[b * H + cb * 16 + c];
        w2[cb] = W2[cb * 16 + c];
    }
    const float b2v = b2[0];

    // per-lane candidate indices for the 4 tiles (4 g-lanes share a value)
    int idx[4];
    const int ibase = b * M + half * 256 + w * 16 + c;
#pragma unroll
    for (int mt = 0; mt < 4; ++mt) idx[mt] = cand_idx[ibase + mt * 64];

    // B base byte-offsets per h-band: lane c reads row h=cb*16+c, k=g*8
    const char* wbase = (const char*)wT;

    // prefetch tile 0 gathers: lane reads k = ks*32 + g*8 .. +8 of its row
    f32x4 buf[8];
    {
        const float* rp = embed + (long)idx[0] * D + g * 8;
#pragma unroll
        for (int ks = 0; ks < 4; ++ks) {
            buf[2 * ks]     = *(const f32x4*)(rp + ks * 32);
            buf[2 * ks + 1] = *(const f32x4*)(rp + ks * 32 + 4);
        }
    }

#pragma unroll
    for (int mt = 0; mt < 4; ++mt) {
        // pack current gathers -> A fragments
        bf16x8 afr[4];
#pragma unroll
        for (int ks = 0; ks < 4; ++ks) {
            u32x4 u;
            u.x = pack2bf(buf[2 * ks].x, buf[2 * ks].y);
            u.y = pack2bf(buf[2 * ks].z, buf[2 * ks].w);
            u.z = pack2bf(buf[2 * ks + 1].x, buf[2 * ks + 1].y);
            u.w = pack2bf(buf[2 * ks + 1].z, buf[2 * ks + 1].w);
            afr[ks] = __builtin_bit_cast(bf16x8, u);
        }
        // prefetch next tile under this tile's MFMA + epilogue
        if (mt < 3) {
            const float* rp = embed + (long)idx[mt + 1] * D + g * 8;
#pragma unroll
            for (int ks = 0; ks < 4; ++ks) {
                buf[2 * ks]     = *(const f32x4*)(rp + ks * 32);
                buf[2 * ks + 1] = *(const f32x4*)(rp + ks * 32 + 4);
            }
        }

        f32x4 acc[8];
#pragma unroll
        for (int cb = 0; cb < 8; ++cb) acc[cb] = (f32x4){0.f, 0.f, 0.f, 0.f};
        // B direct from global: per cb one voffset, ks folds into imm offset
#pragma unroll
        for (int cb = 0; cb < 8; ++cb) {
            const char* bp = wbase + ((cb * 16 + c) << 8) + (g << 4);
#pragma unroll
            for (int ks = 0; ks < 4; ++ks) {
                const bf16x8 bv = *(const bf16x8*)(bp + ks * 64);
                acc[cb] = __builtin_amdgcn_mfma_f32_16x16x32_bf16(afr[ks], bv, acc[cb], 0, 0, 0);
            }
        }

        // epilogue: relu(qh + acc) . W2 ; butterfly-reduce over 16 c-lanes
        float s0 = 0.f, s1 = 0.f, s2 = 0.f, s3 = 0.f;
#pragma unroll
        for (int cb = 0; cb < 8; ++cb) {
            s0 = fmaf(fmaxf(qv[cb] + acc[cb][0], 0.f), w2[cb], s0);
            s1 = fmaf(fmaxf(qv[cb] + acc[cb][1], 0.f), w2[cb], s1);
            s2 = fmaf(fmaxf(qv[cb] + acc[cb][2], 0.f), w2[cb], s2);
            s3 = fmaf(fmaxf(qv[cb] + acc[cb][3], 0.f), w2[cb], s3);
        }
#pragma unroll
        for (int off = 1; off <= 8; off <<= 1) {
            s0 += __shfl_xor(s0, off);
            s1 += __shfl_xor(s1, off);
            s2 += __shfl_xor(s2, off);
            s3 += __shfl_xor(s3, off);
        }
        if (c == 0) {
            float* out = scores + b * M + half * 256 + mt * 64 + w * 16 + g * 4;
            out[0] = s0 + b2v;
            out[1] = s1 + b2v;
            out[2] = s2 + b2v;
            out[3] = s3 + b2v;
        }
    }
}

// ---------------------------------------------------------------------------
// Phase 3a: approximate top-16 shortlist positions per row (1 wave/row)
// ---------------------------------------------------------------------------
__global__ void topk16_kernel(const float* __restrict__ scores,
                              int* __restrict__ shortpos) {
    const int b = blockIdx.x;
    const int lane = threadIdx.x;
    const float* row = scores + b * M;
    float v[8];
    {
        const float4 x0 = ((const float4*)row)[lane * 2];
        const float4 x1 = ((const float4*)row)[lane * 2 + 1];
        v[0] = x0.x; v[1] = x0.y; v[2] = x0.z; v[3] = x0.w;
        v[4] = x1.x; v[5] = x1.y; v[6] = x1.z; v[7] = x1.w;
    }
    for (int kk = 0; kk < SHORT; ++kk) {
        float bv = v[0];
        int bi = lane * 8;
#pragma unroll
        for (int j = 1; j < 8; ++j)
            if (v[j] > bv) { bv = v[j]; bi = lane * 8 + j; }
#pragma unroll
        for (int off = 32; off >= 1; off >>= 1) {
            const float ov = __shfl_xor(bv, off);
            const int   oi = __shfl_xor(bi, off);
            if (ov > bv || (ov == bv && oi < bi)) { bv = ov; bi = oi; }
        }
        if (lane == 0) shortpos[b * SHORT + kk] = bi;
        if ((bi >> 3) == lane) v[bi & 7] = -3.402823466e38f;
    }
}

// ---------------------------------------------------------------------------
// Phase 3b: exact fp32 rescore of shortlist, top-k with lax.top_k semantics
// ---------------------------------------------------------------------------
__global__ __launch_bounds__(128)
void refine_kernel(const float* __restrict__ embed,
                   const float* __restrict__ W1,
                   const float* __restrict__ W2,
                   const float* __restrict__ qh,
                   const int* __restrict__ cand_idx,
                   const int* __restrict__ shortpos,
                   const int* __restrict__ topk_ptr,
                   int* __restrict__ top_nodes) {
    __shared__ float crows[SHORT][D];
    __shared__ float red[SHORT][D];
    __shared__ int spos[SHORT];
    const int b = blockIdx.x;
    const int t = threadIdx.x;

    if (t < SHORT) spos[t] = shortpos[b * SHORT + t];
    __syncthreads();
    {
        const int cc = t >> 3;
        const int d0 = (t & 7) * 16;
        const long node = cand_idx[b * M + spos[cc]];
        const float4* rp = (const float4*)(embed + node * D);
        float4* wp = (float4*)&crows[cc][d0];
#pragma unroll
        for (int j = 0; j < 4; ++j) wp[j] = rp[d0 / 4 + j];
    }
    __syncthreads();

    float acc[SHORT];
#pragma unroll
    for (int cc = 0; cc < SHORT; ++cc) acc[cc] = 0.f;
    const float* W1bot = W1 + (long)D * H;
    for (int d = 0; d < D; ++d) {
        const float w1v = W1bot[d * H + t];
#pragma unroll
        for (int cc = 0; cc < SHORT; ++cc)
            acc[cc] = fmaf(crows[cc][d], w1v, acc[cc]);
    }
    const float qv = qh[b * H + t];
    const float w2 = W2[t];
#pragma unroll
    for (int cc = 0; cc < SHORT; ++cc)
        red[cc][t] = fmaxf(qv + acc[cc], 0.f) * w2;
    __syncthreads();

    if (t < 64) {
#pragma unroll
        for (int cc = 0; cc < SHORT; ++cc) {
            float v = red[cc][t] + red[cc][t + 64];
#pragma unroll
            for (int off = 32; off >= 1; off >>= 1) v += __shfl_xor(v, off);
            if (t == 0) red[cc][0] = v;
        }
    }
    __syncthreads();

    if (t == 0) {
        int k = *topk_ptr;
        if (k > K_MAX) k = K_MAX;
        unsigned used = 0;
        for (int kk = 0; kk < K_MAX; ++kk) {
            if (kk < k) {
                int best = -1, bpos = 0x7fffffff;
                float bv = 0.f;
                for (int cc = 0; cc < SHORT; ++cc) {
                    if (used & (1u << cc)) continue;
                    const float v = red[cc][0];
                    const int p = spos[cc];
                    if (best < 0 || v > bv || (v == bv && p < bpos)) {
                        best = cc; bv = v; bpos = p;
                    }
                }
                used |= 1u << best;
                top_nodes[b * K_MAX + kk] = cand_idx[b * M + bpos];
            } else {
                top_nodes[b * K_MAX + kk] = -1;
            }
        }
    }
}

// ---------------------------------------------------------------------------
// Phase 4: zero the selected rows (after fused copy + refine)
// ---------------------------------------------------------------------------
__global__ void zero_rows_kernel(const int* __restrict__ top_nodes,
                                 float* __restrict__ masked) {
    const int node = top_nodes[blockIdx.x];
    if (node < 0) return;
    masked[(long)node * D + threadIdx.x] = 0.f;
}

// ---------------------------------------------------------------------------
extern "C" void kernel_launch(void* const* d_in, const int* in_sizes, int n_in,
                              void* d_out, int out_size, void* d_ws, size_t ws_size,
                              hipStream_t stream) {
    const float* embed     = (const float*)d_in[0];
    const float* node_feat = (const float*)d_in[1];
    const float* W1        = (const float*)d_in[2];
    const float* b1        = (const float*)d_in[3];
    const float* W2        = (const float*)d_in[4];
    const float* b2        = (const float*)d_in[5];
    const int*   query_idx = (const int*)d_in[6];
    const int*   cand_idx  = (const int*)d_in[7];
    const int*   topk_ptr  = (const int*)d_in[8];

    float* scores = (float*)d_out;                 // B*M
    float* masked = (float*)d_out + (long)BQ * M;  // N*D

    // ws layout
    char* p = (char*)d_ws;
    float*          qh        = (float*)p;          p += (long)BQ * H * 4;
    int*            shortpos  = (int*)p;            p += (long)BQ * SHORT * 4;
    int*            top_nodes = (int*)p;            p += (long)BQ * K_MAX * 4;
    unsigned short* wT        = (unsigned short*)p;

    wconv_kernel<<<(H * D) / 256, 256, 0, stream>>>(W1, wT);
    qproj_kernel<<<BQ, H, 0, stream>>>(embed, W1, b1, query_idx, qh);

    fused_kernel<<<NSCORE + NCOPY, 256, 0, stream>>>(
        embed, wT, W2, b2, cand_idx, qh, scores,
        (const f32x4*)node_feat, (f32x4*)masked);

    topk16_kernel<<<BQ, 64, 0, stream>>>(scores, shortpos);
    refine_kernel<<<BQ, 128, 0, stream>>>(embed, W1, W2, qh, cand_idx,
                                          shortpos, topk_ptr, top_nodes);
    zero_rows_kernel<<<BQ * K_MAX, D, 0, stream>>>(top_nodes, masked);
}

// Round 11
// 197.701 us; speedup vs baseline: 2.8100x; 2.8100x over previous
//
#include <hip/hip_runtime.h>
#include <math.h>

#define D 128
#define H 128
#define BQ 1024
#define M 512
#define NNODES 500000
#define K_MAX 8
#define SHORT 16
#define NSCORE (BQ * 2)            // score units: (row b, m-half), 4 tiles each
#define NCOPY 2048                 // copy units
#define COPY_N4 ((long)NNODES * D / 4)
#define CSTRIDE ((long)NCOPY * 256)

typedef __attribute__((ext_vector_type(8))) short bf16x8;
typedef __attribute__((ext_vector_type(4))) float f32x4;
typedef __attribute__((ext_vector_type(4))) unsigned u32x4;

// RNE fp32->bf16, packed pair
static __device__ __forceinline__ unsigned pack2bf(float a, float b) {
    unsigned ua = __float_as_uint(a);
    unsigned ub = __float_as_uint(b);
    ua = ua + 0x7fffu + ((ua >> 16) & 1u);
    ub = ub + 0x7fffu + ((ub >> 16) & 1u);
    return (ua >> 16) | (ub & 0xffff0000u);
}

// ---------------------------------------------------------------------------
// Phase 0: W1 bottom half -> bf16, h-major, linear image of swizzled LDS tile.
// Swizzle: k-byte inner ^ ((h&15)<<4)  (verified round 7: 0 bank conflicts)
// ---------------------------------------------------------------------------
__global__ void wconv_kernel(const float* __restrict__ W1,
                             unsigned short* __restrict__ wTswz) {
    const int idx = blockIdx.x * 256 + threadIdx.x;  // 0..16383
    const int h = idx >> 7;
    const int inner = (idx & 127) * 2;               // byte offset within row
    const int k = (inner ^ ((h & 15) << 4)) >> 1;
    const float v = W1[(long)(D + k) * H + h];
    wTswz[idx] = (unsigned short)pack2bf(v, 0.f);
}

// ---------------------------------------------------------------------------
// Phase 1: qh[b][h] = b1[h] + embed[query[b]] . W1top   (fp32)
// ---------------------------------------------------------------------------
__global__ void qproj_kernel(const float* __restrict__ embed,
                             const float* __restrict__ W1,
                             const float* __restrict__ b1,
                             const int* __restrict__ query_idx,
                             float* __restrict__ qh) {
    __shared__ float qrow[D];
    const int b = blockIdx.x;
    const int t = threadIdx.x;
    const long qi = query_idx[b];
    qrow[t] = embed[qi * D + t];
    __syncthreads();
    float acc = b1[t];
#pragma unroll 8
    for (int d = 0; d < D; ++d)
        acc = fmaf(qrow[d], W1[d * H + t], acc);
    qh[b * H + t] = acc;
}

// gather one tile's A-slice for this lane into 8 f32x4 regs
#define GATHER(BUF, NODE)                                                    \
    {                                                                        \
        const float* rp_ = embed + (long)(NODE) * D + g * 8;                 \
        BUF[0] = *(const f32x4*)(rp_);                                       \
        BUF[1] = *(const f32x4*)(rp_ + 4);                                   \
        BUF[2] = *(const f32x4*)(rp_ + 32);                                  \
        BUF[3] = *(const f32x4*)(rp_ + 36);                                  \
        BUF[4] = *(const f32x4*)(rp_ + 64);                                  \
        BUF[5] = *(const f32x4*)(rp_ + 68);                                  \
        BUF[6] = *(const f32x4*)(rp_ + 96);                                  \
        BUF[7] = *(const f32x4*)(rp_ + 100);                                 \
    }

// ---------------------------------------------------------------------------
// Phase 2 (FUSED): score + copy heterogeneous launch (round-6 structure).
//   bid odd  -> score unit (2048): (b, m-half), 4 m-tiles, 2-DEEP gather
//               pipeline (bufA/bufB, static indexing), B in swizzled LDS.
//   bid even -> copy unit (2048): nontemporal f32x4 stream, 4x unroll.
// launch_bounds(256,4): VGPR cap 128 (NO spill regime; round 10's (256,8)
// collapsed to 32 VGPR + scratch). LDS 32KB -> 5 blocks/CU.
// ---------------------------------------------------------------------------
__global__ __launch_bounds__(256, 4)
void fused_kernel(const float* __restrict__ embed,
                  const unsigned short* __restrict__ wTswz,
                  const float* __restrict__ W2,
                  const float* __restrict__ b2,
                  const int* __restrict__ cand_idx,
                  const float* __restrict__ qh,
                  float* __restrict__ scores,
                  const f32x4* __restrict__ nf_src,
                  f32x4* __restrict__ nf_dst) {
    __shared__ __align__(16) char Bs[32768];   // [h][k] bf16, swizzled
    const int bid = blockIdx.x;
    const int t   = threadIdx.x;

    if ((bid & 1) == 0) {
        // ---------------- copy unit: nontemporal streaming, 4x unroll ------
        const int cid = bid >> 1;                     // 0..NCOPY-1
        long i = (long)cid * 256 + t;
        for (; i + 3 * CSTRIDE < COPY_N4; i += 4 * CSTRIDE) {
            const f32x4 v0 = __builtin_nontemporal_load(&nf_src[i]);
            const f32x4 v1 = __builtin_nontemporal_load(&nf_src[i + CSTRIDE]);
            const f32x4 v2 = __builtin_nontemporal_load(&nf_src[i + 2 * CSTRIDE]);
            const f32x4 v3 = __builtin_nontemporal_load(&nf_src[i + 3 * CSTRIDE]);
            __builtin_nontemporal_store(v0, &nf_dst[i]);
            __builtin_nontemporal_store(v1, &nf_dst[i + CSTRIDE]);
            __builtin_nontemporal_store(v2, &nf_dst[i + 2 * CSTRIDE]);
            __builtin_nontemporal_store(v3, &nf_dst[i + 3 * CSTRIDE]);
        }
        for (; i < COPY_N4; i += CSTRIDE) {
            const f32x4 v = __builtin_nontemporal_load(&nf_src[i]);
            __builtin_nontemporal_store(v, &nf_dst[i]);
        }
        return;
    }

    // ------------------- score unit: (b, half), 4 m-tiles ------------------
    const int sid  = bid >> 1;           // 0..NSCORE-1
    const int b    = sid >> 1;           // 0..BQ-1
    const int half = sid & 1;            // m-offset half*256

    {   // stage B once: linear copy of pre-swizzled bf16 W1bot (32 KB)
#pragma unroll
        for (int i = 0; i < 8; ++i) {
            const int c = i * 256 + t;
            const uint4 v = ((const uint4*)wTswz)[c];
            *(uint4*)(Bs + (size_t)c * 16) = v;
        }
    }

    const int lane = t & 63;
    const int w    = t >> 6;       // wave id = edge band within tile
    const int g    = lane >> 4;    // k-group
    const int c    = lane & 15;    // row (edge) / col (h) within band
    const int sw   = c << 4;       // full-nibble swizzle (matches wconv)

    // hoist per-row operands: qh and W2 at h = cb*16+c
    float qv[8], w2[8];
#pragma unroll
    for (int cb = 0; cb < 8; ++cb) {
        qv[cb] = qh[b * H + cb * 16 + c];
        w2[cb] = W2[cb * 16 + c];
    }
    const float b2v = b2[0];

    // per-lane candidate indices for the 4 tiles (4 g-lanes share a value)
    int idx[4];
    const int ibase = b * M + half * 256 + w * 16 + c;
#pragma unroll
    for (int mt = 0; mt < 4; ++mt) idx[mt] = cand_idx[ibase + mt * 64];

    __syncthreads();   // Bs ready

    // 2-deep gather pipeline: tiles 0,1 in flight before first compute
    f32x4 bufA[8], bufB[8];
    GATHER(bufA, idx[0]);
    GATHER(bufB, idx[1]);

#pragma unroll
    for (int mt = 0; mt < 4; ++mt) {           // fully unrolled, static mt
        // pack current tile's gathers -> A fragments (bufA if mt even)
        bf16x8 afr[4];
#pragma unroll
        for (int ks = 0; ks < 4; ++ks) {
            const f32x4 lo = (mt & 1) ? bufB[2 * ks]     : bufA[2 * ks];
            const f32x4 hi = (mt & 1) ? bufB[2 * ks + 1] : bufA[2 * ks + 1];
            u32x4 u;
            u.x = pack2bf(lo.x, lo.y);
            u.y = pack2bf(lo.z, lo.w);
            u.z = pack2bf(hi.x, hi.y);
            u.w = pack2bf(hi.z, hi.w);
            afr[ks] = __builtin_bit_cast(bf16x8, u);
        }
        // refill the buffer just consumed with tile mt+2 (under MFMA+epilogue)
        if (mt == 0) GATHER(bufA, idx[2]);
        if (mt == 1) GATHER(bufB, idx[3]);

        f32x4 acc[8];
#pragma unroll
        for (int cb = 0; cb < 8; ++cb) acc[cb] = (f32x4){0.f, 0.f, 0.f, 0.f};
#pragma unroll
        for (int ks = 0; ks < 4; ++ks) {
            const int koff = (ks * 64 + g * 16) ^ sw;
#pragma unroll
            for (int cb = 0; cb < 8; ++cb) {
                const bf16x8 bv = *(const bf16x8*)(Bs + ((cb * 16 + c) << 8) + koff);
                acc[cb] = __builtin_amdgcn_mfma_f32_16x16x32_bf16(afr[ks], bv, acc[cb], 0, 0, 0);
            }
        }

        // epilogue: relu(qh + acc) . W2 ; butterfly-reduce over 16 c-lanes
        float s0 = 0.f, s1 = 0.f, s2 = 0.f, s3 = 0.f;
#pragma unroll
        for (int cb = 0; cb < 8; ++cb) {
            s0 = fmaf(fmaxf(qv[cb] + acc[cb][0], 0.f), w2[cb], s0);
            s1 = fmaf(fmaxf(qv[cb] + acc[cb][1], 0.f), w2[cb], s1);
            s2 = fmaf(fmaxf(qv[cb] + acc[cb][2], 0.f), w2[cb], s2);
            s3 = fmaf(fmaxf(qv[cb] + acc[cb][3], 0.f), w2[cb], s3);
        }
#pragma unroll
        for (int off = 1; off <= 8; off <<= 1) {
            s0 += __shfl_xor(s0, off);
            s1 += __shfl_xor(s1, off);
            s2 += __shfl_xor(s2, off);
            s3 += __shfl_xor(s3, off);
        }
        if (c == 0) {
            float* out = scores + b * M + half * 256 + mt * 64 + w * 16 + g * 4;
            out[0] = s0 + b2v;
            out[1] = s1 + b2v;
            out[2] = s2 + b2v;
            out[3] = s3 + b2v;
        }
    }
}

// ---------------------------------------------------------------------------
// Phase 3a: approximate top-16 shortlist positions per row (1 wave/row)
// ---------------------------------------------------------------------------
__global__ void topk16_kernel(const float* __restrict__ scores,
                              int* __restrict__ shortpos) {
    const int b = blockIdx.x;
    const int lane = threadIdx.x;
    const float* row = scores + b * M;
    float v[8];
    {
        const float4 x0 = ((const float4*)row)[lane * 2];
        const float4 x1 = ((const float4*)row)[lane * 2 + 1];
        v[0] = x0.x; v[1] = x0.y; v[2] = x0.z; v[3] = x0.w;
        v[4] = x1.x; v[5] = x1.y; v[6] = x1.z; v[7] = x1.w;
    }
    for (int kk = 0; kk < SHORT; ++kk) {
        float bv = v[0];
        int bi = lane * 8;
#pragma unroll
        for (int j = 1; j < 8; ++j)
            if (v[j] > bv) { bv = v[j]; bi = lane * 8 + j; }
#pragma unroll
        for (int off = 32; off >= 1; off >>= 1) {
            const float ov = __shfl_xor(bv, off);
            const int   oi = __shfl_xor(bi, off);
            if (ov > bv || (ov == bv && oi < bi)) { bv = ov; bi = oi; }
        }
        if (lane == 0) shortpos[b * SHORT + kk] = bi;
        if ((bi >> 3) == lane) v[bi & 7] = -3.402823466e38f;
    }
}

// ---------------------------------------------------------------------------
// Phase 3b: exact fp32 rescore of shortlist, top-k with lax.top_k semantics
// ---------------------------------------------------------------------------
__global__ __launch_bounds__(128)
void refine_kernel(const float* __restrict__ embed,
                   const float* __restrict__ W1,
                   const float* __restrict__ W2,
                   const float* __restrict__ qh,
                   const int* __restrict__ cand_idx,
                   const int* __restrict__ shortpos,
                   const int* __restrict__ topk_ptr,
                   int* __restrict__ top_nodes) {
    __shared__ float crows[SHORT][D];
    __shared__ float red[SHORT][D];
    __shared__ int spos[SHORT];
    const int b = blockIdx.x;
    const int t = threadIdx.x;

    if (t < SHORT) spos[t] = shortpos[b * SHORT + t];
    __syncthreads();
    {
        const int cc = t >> 3;
        const int d0 = (t & 7) * 16;
        const long node = cand_idx[b * M + spos[cc]];
        const float4* rp = (const float4*)(embed + node * D);
        float4* wp = (float4*)&crows[cc][d0];
#pragma unroll
        for (int j = 0; j < 4; ++j) wp[j] = rp[d0 / 4 + j];
    }
    __syncthreads();

    float acc[SHORT];
#pragma unroll
    for (int cc = 0; cc < SHORT; ++cc) acc[cc] = 0.f;
    const float* W1bot = W1 + (long)D * H;
    for (int d = 0; d < D; ++d) {
        const float w1v = W1bot[d * H + t];
#pragma unroll
        for (int cc = 0; cc < SHORT; ++cc)
            acc[cc] = fmaf(crows[cc][d], w1v, acc[cc]);
    }
    const float qv = qh[b * H + t];
    const float w2 = W2[t];
#pragma unroll
    for (int cc = 0; cc < SHORT; ++cc)
        red[cc][t] = fmaxf(qv + acc[cc], 0.f) * w2;
    __syncthreads();

    if (t < 64) {
#pragma unroll
        for (int cc = 0; cc < SHORT; ++cc) {
            float v = red[cc][t] + red[cc][t + 64];
#pragma unroll
            for (int off = 32; off >= 1; off >>= 1) v += __shfl_xor(v, off);
            if (t == 0) red[cc][0] = v;
        }
    }
    __syncthreads();

    if (t == 0) {
        int k = *topk_ptr;
        if (k > K_MAX) k = K_MAX;
        unsigned used = 0;
        for (int kk = 0; kk < K_MAX; ++kk) {
            if (kk < k) {
                int best = -1, bpos = 0x7fffffff;
                float bv = 0.f;
                for (int cc = 0; cc < SHORT; ++cc) {
                    if (used & (1u << cc)) continue;
                    const float v = red[cc][0];
                    const int p = spos[cc];
                    if (best < 0 || v > bv || (v == bv && p < bpos)) {
                        best = cc; bv = v; bpos = p;
                    }
                }
                used |= 1u << best;
                top_nodes[b * K_MAX + kk] = cand_idx[b * M + bpos];
            } else {
                top_nodes[b * K_MAX + kk] = -1;
            }
        }
    }
}

// ---------------------------------------------------------------------------
// Phase 4: zero the selected rows (after fused copy + refine)
// ---------------------------------------------------------------------------
__global__ void zero_rows_kernel(const int* __restrict__ top_nodes,
                                 float* __restrict__ masked) {
    const int node = top_nodes[blockIdx.x];
    if (node < 0) return;
    masked[(long)node * D + threadIdx.x] = 0.f;
}

// ---------------------------------------------------------------------------
extern "C" void kernel_launch(void* const* d_in, const int* in_sizes, int n_in,
                              void* d_out, int out_size, void* d_ws, size_t ws_size,
                              hipStream_t stream) {
    const float* embed     = (const float*)d_in[0];
    const float* node_feat = (const float*)d_in[1];
    const float* W1        = (const float*)d_in[2];
    const float* b1        = (const float*)d_in[3];
    const float* W2        = (const float*)d_in[4];
    const float* b2        = (const float*)d_in[5];
    const int*   query_idx = (const int*)d_in[6];
    const int*   cand_idx  = (const int*)d_in[7];
    const int*   topk_ptr  = (const int*)d_in[8];

    float* scores = (float*)d_out;                 // B*M
    float* masked = (float*)d_out + (long)BQ * M;  // N*D

    // ws layout
    char* p = (char*)d_ws;
    float*          qh        = (float*)p;          p += (long)BQ * H * 4;
    int*            shortpos  = (int*)p;            p += (long)BQ * SHORT * 4;
    int*            top_nodes = (int*)p;            p += (long)BQ * K_MAX * 4;
    unsigned short* wTswz     = (unsigned short*)p;

    wconv_kernel<<<(H * D) / 256, 256, 0, stream>>>(W1, wTswz);
    qproj_kernel<<<BQ, H, 0, stream>>>(embed, W1, b1, query_idx, qh);

    fused_kernel<<<NSCORE + NCOPY, 256, 0, stream>>>(
        embed, wTswz, W2, b2, cand_idx, qh, scores,
        (const f32x4*)node_feat, (f32x4*)masked);

    topk16_kernel<<<BQ, 64, 0, stream>>>(scores, shortpos);
    refine_kernel<<<BQ, 128, 0, stream>>>(embed, W1, W2, qh, cand_idx,
                                          shortpos, topk_ptr, top_nodes);
    zero_rows_kernel<<<BQ * K_MAX, D, 0, stream>>>(top_nodes, masked);
}

// Round 12
// 188.340 us; speedup vs baseline: 2.9496x; 1.0497x over previous
//
#include <hip/hip_runtime.h>
#include <math.h>

#define D 128
#define H 128
#define BQ 1024
#define M 512
#define NNODES 500000
#define K_MAX 8
#define SHORT 16
#define NCOPYP 1536                // persistent copy blocks, FIRST in grid
#define NSCORE (BQ * 2)            // score units: (row b, m-half), 4 tiles each
#define COPY_N4 ((long)NNODES * D / 4)
#define CSTRIDE ((long)NCOPYP * 256)

typedef __attribute__((ext_vector_type(8))) short bf16x8;
typedef __attribute__((ext_vector_type(4))) float f32x4;
typedef __attribute__((ext_vector_type(4))) unsigned u32x4;

// RNE fp32->bf16, packed pair
static __device__ __forceinline__ unsigned pack2bf(float a, float b) {
    unsigned ua = __float_as_uint(a);
    unsigned ub = __float_as_uint(b);
    ua = ua + 0x7fffu + ((ua >> 16) & 1u);
    ub = ub + 0x7fffu + ((ub >> 16) & 1u);
    return (ua >> 16) | (ub & 0xffff0000u);
}

// ---------------------------------------------------------------------------
// Phase 0: W1 bottom half -> bf16, h-major, linear image of swizzled LDS tile.
// Swizzle: k-byte inner ^ ((h&15)<<4)  (verified round 7: 0 bank conflicts)
// ---------------------------------------------------------------------------
__global__ void wconv_kernel(const float* __restrict__ W1,
                             unsigned short* __restrict__ wTswz) {
    const int idx = blockIdx.x * 256 + threadIdx.x;  // 0..16383
    const int h = idx >> 7;
    const int inner = (idx & 127) * 2;               // byte offset within row
    const int k = (inner ^ ((h & 15) << 4)) >> 1;
    const float v = W1[(long)(D + k) * H + h];
    wTswz[idx] = (unsigned short)pack2bf(v, 0.f);
}

// ---------------------------------------------------------------------------
// Phase 1: qh[b][h] = b1[h] + embed[query[b]] . W1top   (fp32)
// ---------------------------------------------------------------------------
__global__ void qproj_kernel(const float* __restrict__ embed,
                             const float* __restrict__ W1,
                             const float* __restrict__ b1,
                             const int* __restrict__ query_idx,
                             float* __restrict__ qh) {
    __shared__ float qrow[D];
    const int b = blockIdx.x;
    const int t = threadIdx.x;
    const long qi = query_idx[b];
    qrow[t] = embed[qi * D + t];
    __syncthreads();
    float acc = b1[t];
#pragma unroll 8
    for (int d = 0; d < D; ++d)
        acc = fmaf(qrow[d], W1[d * H + t], acc);
    qh[b * H + t] = acc;
}

// ---------------------------------------------------------------------------
// Phase 2 (FUSED, PARTITIONED): blocks [0,NCOPYP) = persistent nt copy
// (dispatched first -> ~6 copy blocks/CU = 24 streaming waves/CU); blocks
// [NCOPYP, NCOPYP+NSCORE) = short score units filling leftover wave slots.
// Score body = round-6 1-deep pipeline (VGPR 60, no spill).
// ---------------------------------------------------------------------------
__global__ __launch_bounds__(256, 4)
void fused_kernel(const float* __restrict__ embed,
                  const unsigned short* __restrict__ wTswz,
                  const float* __restrict__ W2,
                  const float* __restrict__ b2,
                  const int* __restrict__ cand_idx,
                  const float* __restrict__ qh,
                  float* __restrict__ scores,
                  const f32x4* __restrict__ nf_src,
                  f32x4* __restrict__ nf_dst) {
    __shared__ __align__(16) char Bs[32768];   // [h][k] bf16, swizzled
    const int bid = blockIdx.x;
    const int t   = threadIdx.x;

    if (bid < NCOPYP) {
        // ---------------- copy block: nontemporal streaming, 4x unroll -----
        long i = (long)bid * 256 + t;
        for (; i + 3 * CSTRIDE < COPY_N4; i += 4 * CSTRIDE) {
            const f32x4 v0 = __builtin_nontemporal_load(&nf_src[i]);
            const f32x4 v1 = __builtin_nontemporal_load(&nf_src[i + CSTRIDE]);
            const f32x4 v2 = __builtin_nontemporal_load(&nf_src[i + 2 * CSTRIDE]);
            const f32x4 v3 = __builtin_nontemporal_load(&nf_src[i + 3 * CSTRIDE]);
            __builtin_nontemporal_store(v0, &nf_dst[i]);
            __builtin_nontemporal_store(v1, &nf_dst[i + CSTRIDE]);
            __builtin_nontemporal_store(v2, &nf_dst[i + 2 * CSTRIDE]);
            __builtin_nontemporal_store(v3, &nf_dst[i + 3 * CSTRIDE]);
        }
        for (; i < COPY_N4; i += CSTRIDE) {
            const f32x4 v = __builtin_nontemporal_load(&nf_src[i]);
            __builtin_nontemporal_store(v, &nf_dst[i]);
        }
        return;
    }

    // ------------------- score unit: (b, half), 4 m-tiles ------------------
    const int sid  = bid - NCOPYP;       // 0..NSCORE-1
    const int b    = sid >> 1;           // 0..BQ-1
    const int half = sid & 1;            // m-offset half*256

    {   // stage B once: linear copy of pre-swizzled bf16 W1bot (32 KB)
#pragma unroll
        for (int i = 0; i < 8; ++i) {
            const int c = i * 256 + t;
            const uint4 v = ((const uint4*)wTswz)[c];
            *(uint4*)(Bs + (size_t)c * 16) = v;
        }
    }

    const int lane = t & 63;
    const int w    = t >> 6;       // wave id = edge band within tile
    const int g    = lane >> 4;    // k-group
    const int c    = lane & 15;    // row (edge) / col (h) within band
    const int sw   = c << 4;       // full-nibble swizzle (matches wconv)

    // hoist per-row operands: qh and W2 at h = cb*16+c
    float qv[8], w2[8];
#pragma unroll
    for (int cb = 0; cb < 8; ++cb) {
        qv[cb] = qh[b * H + cb * 16 + c];
        w2[cb] = W2[cb * 16 + c];
    }
    const float b2v = b2[0];

    // per-lane candidate indices for the 4 tiles (4 g-lanes share a value)
    int idx[4];
    const int ibase = b * M + half * 256 + w * 16 + c;
#pragma unroll
    for (int mt = 0; mt < 4; ++mt) idx[mt] = cand_idx[ibase + mt * 64];

    __syncthreads();   // Bs ready

    // 1-deep pipeline: prefetch tile 0
    f32x4 buf[8];
    {
        const float* rp = embed + (long)idx[0] * D + g * 8;
#pragma unroll
        for (int ks = 0; ks < 4; ++ks) {
            buf[2 * ks]     = *(const f32x4*)(rp + ks * 32);
            buf[2 * ks + 1] = *(const f32x4*)(rp + ks * 32 + 4);
        }
    }

#pragma unroll
    for (int mt = 0; mt < 4; ++mt) {
        // pack current gathers -> A fragments
        bf16x8 afr[4];
#pragma unroll
        for (int ks = 0; ks < 4; ++ks) {
            u32x4 u;
            u.x = pack2bf(buf[2 * ks].x, buf[2 * ks].y);
            u.y = pack2bf(buf[2 * ks].z, buf[2 * ks].w);
            u.z = pack2bf(buf[2 * ks + 1].x, buf[2 * ks + 1].y);
            u.w = pack2bf(buf[2 * ks + 1].z, buf[2 * ks + 1].w);
            afr[ks] = __builtin_bit_cast(bf16x8, u);
        }
        // prefetch next tile under this tile's MFMA + epilogue
        if (mt < 3) {
            const float* rp = embed + (long)idx[mt + 1] * D + g * 8;
#pragma unroll
            for (int ks = 0; ks < 4; ++ks) {
                buf[2 * ks]     = *(const f32x4*)(rp + ks * 32);
                buf[2 * ks + 1] = *(const f32x4*)(rp + ks * 32 + 4);
            }
        }

        f32x4 acc[8];
#pragma unroll
        for (int cb = 0; cb < 8; ++cb) acc[cb] = (f32x4){0.f, 0.f, 0.f, 0.f};
#pragma unroll
        for (int ks = 0; ks < 4; ++ks) {
            const int koff = (ks * 64 + g * 16) ^ sw;
#pragma unroll
            for (int cb = 0; cb < 8; ++cb) {
                const bf16x8 bv = *(const bf16x8*)(Bs + ((cb * 16 + c) << 8) + koff);
                acc[cb] = __builtin_amdgcn_mfma_f32_16x16x32_bf16(afr[ks], bv, acc[cb], 0, 0, 0);
            }
        }

        // epilogue: relu(qh + acc) . W2 ; butterfly-reduce over 16 c-lanes
        float s0 = 0.f, s1 = 0.f, s2 = 0.f, s3 = 0.f;
#pragma unroll
        for (int cb = 0; cb < 8; ++cb) {
            s0 = fmaf(fmaxf(qv[cb] + acc[cb][0], 0.f), w2[cb], s0);
            s1 = fmaf(fmaxf(qv[cb] + acc[cb][1], 0.f), w2[cb], s1);
            s2 = fmaf(fmaxf(qv[cb] + acc[cb][2], 0.f), w2[cb], s2);
            s3 = fmaf(fmaxf(qv[cb] + acc[cb][3], 0.f), w2[cb], s3);
        }
#pragma unroll
        for (int off = 1; off <= 8; off <<= 1) {
            s0 += __shfl_xor(s0, off);
            s1 += __shfl_xor(s1, off);
            s2 += __shfl_xor(s2, off);
            s3 += __shfl_xor(s3, off);
        }
        if (c == 0) {
            float* out = scores + b * M + half * 256 + mt * 64 + w * 16 + g * 4;
            out[0] = s0 + b2v;
            out[1] = s1 + b2v;
            out[2] = s2 + b2v;
            out[3] = s3 + b2v;
        }
    }
}

// ---------------------------------------------------------------------------
// Phase 3a: approximate top-16 shortlist positions per row (1 wave/row)
// ---------------------------------------------------------------------------
__global__ void topk16_kernel(const float* __restrict__ scores,
                              int* __restrict__ shortpos) {
    const int b = blockIdx.x;
    const int lane = threadIdx.x;
    const float* row = scores + b * M;
    float v[8];
    {
        const float4 x0 = ((const float4*)row)[lane * 2];
        const float4 x1 = ((const float4*)row)[lane * 2 + 1];
        v[0] = x0.x; v[1] = x0.y; v[2] = x0.z; v[3] = x0.w;
        v[4] = x1.x; v[5] = x1.y; v[6] = x1.z; v[7] = x1.w;
    }
    for (int kk = 0; kk < SHORT; ++kk) {
        float bv = v[0];
        int bi = lane * 8;
#pragma unroll
        for (int j = 1; j < 8; ++j)
            if (v[j] > bv) { bv = v[j]; bi = lane * 8 + j; }
#pragma unroll
        for (int off = 32; off >= 1; off >>= 1) {
            const float ov = __shfl_xor(bv, off);
            const int   oi = __shfl_xor(bi, off);
            if (ov > bv || (ov == bv && oi < bi)) { bv = ov; bi = oi; }
        }
        if (lane == 0) shortpos[b * SHORT + kk] = bi;
        if ((bi >> 3) == lane) v[bi & 7] = -3.402823466e38f;
    }
}

// ---------------------------------------------------------------------------
// Phase 3b: exact fp32 rescore of shortlist, top-k with lax.top_k semantics
// ---------------------------------------------------------------------------
__global__ __launch_bounds__(128)
void refine_kernel(const float* __restrict__ embed,
                   const float* __restrict__ W1,
                   const float* __restrict__ W2,
                   const float* __restrict__ qh,
                   const int* __restrict__ cand_idx,
                   const int* __restrict__ shortpos,
                   const int* __restrict__ topk_ptr,
                   int* __restrict__ top_nodes) {
    __shared__ float crows[SHORT][D];
    __shared__ float red[SHORT][D];
    __shared__ int spos[SHORT];
    const int b = blockIdx.x;
    const int t = threadIdx.x;

    if (t < SHORT) spos[t] = shortpos[b * SHORT + t];
    __syncthreads();
    {
        const int cc = t >> 3;
        const int d0 = (t & 7) * 16;
        const long node = cand_idx[b * M + spos[cc]];
        const float4* rp = (const float4*)(embed + node * D);
        float4* wp = (float4*)&crows[cc][d0];
#pragma unroll
        for (int j = 0; j < 4; ++j) wp[j] = rp[d0 / 4 + j];
    }
    __syncthreads();

    float acc[SHORT];
#pragma unroll
    for (int cc = 0; cc < SHORT; ++cc) acc[cc] = 0.f;
    const float* W1bot = W1 + (long)D * H;
    for (int d = 0; d < D; ++d) {
        const float w1v = W1bot[d * H + t];
#pragma unroll
        for (int cc = 0; cc < SHORT; ++cc)
            acc[cc] = fmaf(crows[cc][d], w1v, acc[cc]);
    }
    const float qv = qh[b * H + t];
    const float w2 = W2[t];
#pragma unroll
    for (int cc = 0; cc < SHORT; ++cc)
        red[cc][t] = fmaxf(qv + acc[cc], 0.f) * w2;
    __syncthreads();

    if (t < 64) {
#pragma unroll
        for (int cc = 0; cc < SHORT; ++cc) {
            float v = red[cc][t] + red[cc][t + 64];
#pragma unroll
            for (int off = 32; off >= 1; off >>= 1) v += __shfl_xor(v, off);
            if (t == 0) red[cc][0] = v;
        }
    }
    __syncthreads();

    if (t == 0) {
        int k = *topk_ptr;
        if (k > K_MAX) k = K_MAX;
        unsigned used = 0;
        for (int kk = 0; kk < K_MAX; ++kk) {
            if (kk < k) {
                int best = -1, bpos = 0x7fffffff;
                float bv = 0.f;
                for (int cc = 0; cc < SHORT; ++cc) {
                    if (used & (1u << cc)) continue;
                    const float v = red[cc][0];
                    const int p = spos[cc];
                    if (best < 0 || v > bv || (v == bv && p < bpos)) {
                        best = cc; bv = v; bpos = p;
                    }
                }
                used |= 1u << best;
                top_nodes[b * K_MAX + kk] = cand_idx[b * M + bpos];
            } else {
                top_nodes[b * K_MAX + kk] = -1;
            }
        }
    }
}

// ---------------------------------------------------------------------------
// Phase 4: zero the selected rows (after fused copy + refine)
// ---------------------------------------------------------------------------
__global__ void zero_rows_kernel(const int* __restrict__ top_nodes,
                                 float* __restrict__ masked) {
    const int node = top_nodes[blockIdx.x];
    if (node < 0) return;
    masked[(long)node * D + threadIdx.x] = 0.f;
}

// ---------------------------------------------------------------------------
extern "C" void kernel_launch(void* const* d_in, const int* in_sizes, int n_in,
                              void* d_out, int out_size, void* d_ws, size_t ws_size,
                              hipStream_t stream) {
    const float* embed     = (const float*)d_in[0];
    const float* node_feat = (const float*)d_in[1];
    const float* W1        = (const float*)d_in[2];
    const float* b1        = (const float*)d_in[3];
    const float* W2        = (const float*)d_in[4];
    const float* b2        = (const float*)d_in[5];
    const int*   query_idx = (const int*)d_in[6];
    const int*   cand_idx  = (const int*)d_in[7];
    const int*   topk_ptr  = (const int*)d_in[8];

    float* scores = (float*)d_out;                 // B*M
    float* masked = (float*)d_out + (long)BQ * M;  // N*D

    // ws layout
    char* p = (char*)d_ws;
    float*          qh        = (float*)p;          p += (long)BQ * H * 4;
    int*            shortpos  = (int*)p;            p += (long)BQ * SHORT * 4;
    int*            top_nodes = (int*)p;            p += (long)BQ * K_MAX * 4;
    unsigned short* wTswz     = (unsigned short*)p;

    wconv_kernel<<<(H * D) / 256, 256, 0, stream>>>(W1, wTswz);
    qproj_kernel<<<BQ, H, 0, stream>>>(embed, W1, b1, query_idx, qh);

    fused_kernel<<<NCOPYP + NSCORE, 256, 0, stream>>>(
        embed, wTswz, W2, b2, cand_idx, qh, scores,
        (const f32x4*)node_feat, (f32x4*)masked);

    topk16_kernel<<<BQ, 64, 0, stream>>>(scores, shortpos);
    refine_kernel<<<BQ, 128, 0, stream>>>(embed, W1, W2, qh, cand_idx,
                                          shortpos, topk_ptr, top_nodes);
    zero_rows_kernel<<<BQ * K_MAX, D, 0, stream>>>(top_nodes, masked);
}